// Round 7
// baseline (504.879 us; speedup 1.0000x reference)
//
#include <hip/hip_runtime.h>

// PoolHiddenNet round 7: r6 pipeline with the race fixed.
// 3 LDS buffers, distance-2 DMA prefetch, manual `s_waitcnt vmcnt(4) lgkmcnt(0)`
// + raw `s_barrier` (lgkmcnt(0) is REQUIRED: without it a wave's pending
// ds_reads can cross the barrier and race with the next tile's DMA writes —
// r6 failed with absmax 0.375 from exactly this). Tile k+2 stays in flight
// across the barrier. Prep fused (Abf build + Wm transpose).
// XCD swizzle + XOR bank swizzle + segment-max epilogue proven r3-r5.

typedef __bf16 bf16x8 __attribute__((ext_vector_type(8)));
typedef float floatx4 __attribute__((ext_vector_type(4)));

constexpr int NR = 102400;
constexpr int NG = 2048;
constexpr int E  = 128;
constexpr int H  = 512;
constexpr int KD = 640;
constexpr int BM = 128, BN = 128, BK = 32;
constexpr int KT = KD / BK;   // 20

__device__ inline unsigned short f2bf(float f) {
    unsigned u = __float_as_uint(f);
    u += 0x7FFF + ((u >> 16) & 1u);   // RNE (finite inputs)
    return (unsigned short)(u >> 16);
}

__device__ inline void async16(const void* g, void* l) {
    __builtin_amdgcn_global_load_lds(
        (const __attribute__((address_space(1))) unsigned int*)g,
        (__attribute__((address_space(3))) unsigned int*)l, 16, 0, 0);
}

// ---------------- prep: Abf build (800 blocks, if doAbf) + WmT transpose (80 blocks) ----------------
__global__ __launch_bounds__(256) void prep(
    const float* __restrict__ hist_enc, const float* __restrict__ pos,
    const int* __restrict__ sse, const float* __restrict__ Ws,
    const float* __restrict__ bs, const float* __restrict__ Wm,
    unsigned short* __restrict__ WmT, unsigned short* __restrict__ Abf, int doAbf)
{
    const int b = blockIdx.x;
    const int t = threadIdx.x;
    if (doAbf && b < 800) {
        __shared__ float relRow[BM][2];
        const int rowBase = b * BM;
        if (t < BM) {
            const int i = rowBase + t;
            int l = 0, r = NG + 1;
            while (l < r) { int m = (l + r) >> 1; if (sse[m] <= i) l = m + 1; else r = m; }
            const int a = sse[l - 1];
            relRow[t][0] = pos[2 * i + 0] - pos[2 * a + 0];
            relRow[t][1] = pos[2 * i + 1] - pos[2 * a + 1];
        }
        __syncthreads();
#pragma unroll 4
        for (int j = 0; j < 32; ++j) {
            const int c = j * 256 + t;
            const int row = c >> 6, col = (c & 63) * 8;
            const float4 f0 = *(const float4*)&hist_enc[(size_t)(rowBase + row) * H + col];
            const float4 f1 = *(const float4*)&hist_enc[(size_t)(rowBase + row) * H + col + 4];
            unsigned short ub[8] = {f2bf(f0.x), f2bf(f0.y), f2bf(f0.z), f2bf(f0.w),
                                    f2bf(f1.x), f2bf(f1.y), f2bf(f1.z), f2bf(f1.w)};
            *(uint4*)&Abf[(size_t)(rowBase + row) * KD + col] = *(const uint4*)ub;
        }
#pragma unroll 2
        for (int j = 0; j < 8; ++j) {
            const int c = j * 256 + t;
            const int row = c >> 4, e = (c & 15) * 8;
            const float r0 = relRow[row][0], r1 = relRow[row][1];
            const float4 w0a = *(const float4*)&Ws[e],     w0b = *(const float4*)&Ws[e + 4];
            const float4 w1a = *(const float4*)&Ws[E + e], w1b = *(const float4*)&Ws[E + e + 4];
            const float4 ba  = *(const float4*)&bs[e],     bb  = *(const float4*)&bs[e + 4];
            unsigned short ub[8] = {
                f2bf(fmaxf(r0 * w0a.x + r1 * w1a.x + ba.x, 0.f)),
                f2bf(fmaxf(r0 * w0a.y + r1 * w1a.y + ba.y, 0.f)),
                f2bf(fmaxf(r0 * w0a.z + r1 * w1a.z + ba.z, 0.f)),
                f2bf(fmaxf(r0 * w0a.w + r1 * w1a.w + ba.w, 0.f)),
                f2bf(fmaxf(r0 * w0b.x + r1 * w1b.x + bb.x, 0.f)),
                f2bf(fmaxf(r0 * w0b.y + r1 * w1b.y + bb.y, 0.f)),
                f2bf(fmaxf(r0 * w0b.z + r1 * w1b.z + bb.z, 0.f)),
                f2bf(fmaxf(r0 * w0b.w + r1 * w1b.w + bb.w, 0.f))};
            *(uint4*)&Abf[(size_t)(rowBase + row) * KD + H + e] = *(const uint4*)ub;
        }
    } else {
        const int bb = doAbf ? (b - 800) : b;
        if (bb < 0 || bb >= 80) return;
        __shared__ float tile[64][65];
        const int kb = (bb % 10) * 64, nb = (bb / 10) * 64;
        const int tx = t & 63, tq = t >> 6;
#pragma unroll
        for (int i = 0; i < 16; ++i) {
            const int k = tq * 16 + i;
            tile[k][tx] = Wm[(size_t)(kb + k) * H + nb + tx];
        }
        __syncthreads();
#pragma unroll
        for (int i = 0; i < 16; ++i) {
            const int n = tq * 16 + i;
            WmT[(size_t)(nb + n) * KD + kb + tx] = f2bf(tile[tx][n]);
        }
    }
}

// ---------------- main: GEMM + segment-max, 3-buffer vmcnt pipeline ----------------
__global__ __launch_bounds__(256) void pool_mfma5(
    const unsigned short* __restrict__ Abf,   // (NR, 640) bf16
    const int*   __restrict__ sse,
    const unsigned short* __restrict__ WmT,   // (512, 640) bf16
    const float* __restrict__ bm,
    float*       __restrict__ out)            // (2048, 512) fp32, zeroed
{
    __shared__ __attribute__((aligned(16))) unsigned short As3[3][BM * BK]; // 3 x 8 KB
    __shared__ __attribute__((aligned(16))) unsigned short Bs3[3][BN * BK]; // 3 x 8 KB
    __shared__ int segRow[BM];
    __shared__ int bnd[3];
    __shared__ int Pmax[4][BN + 4];

    const int t = threadIdx.x;
    // XCD swizzle (proven): 4 column-siblings of a row-tile share bid%8.
    const int bid     = blockIdx.x;
    const int rowTile = (bid >> 5) * 8 + (bid & 7);
    const int colTile = (bid >> 3) & 3;
    const int rowBase = rowTile * BM;
    const int cTile   = colTile * BN;

    const int lane  = t & 63;
    const int wv    = t >> 6;
    const int wr    = (wv >> 1) * 64;
    const int wc    = (wv & 1) * 64;
    const int lcol  = lane & 15;
    const int lquad = lane >> 4;

    // DMA staging (r3/r5-proven): wave wv stages rows [wv*32, wv*32+32);
    // source chunk XOR-swizzled so fragment ds_read_b128 is ~2-way only.
    const int sRow0 = wv * 32 + (lane >> 2);
    const int sRow1 = sRow0 + 16;
    const int phys  = lane & 3;
    const int cl0   = phys ^ ((sRow0 >> 1) & 3);
    const int cl1   = phys ^ ((sRow1 >> 1) & 3);
    const unsigned short* gA0 = Abf + (size_t)(rowBase + sRow0) * KD + cl0 * 8;
    const unsigned short* gA1 = Abf + (size_t)(rowBase + sRow1) * KD + cl1 * 8;
    const unsigned short* gB0 = WmT + (size_t)(cTile + sRow0) * KD + cl0 * 8;
    const unsigned short* gB1 = WmT + (size_t)(cTile + sRow1) * KD + cl1 * 8;

    auto issue = [&](int kt) {
        const int buf = kt % 3;
        const int ko  = kt * BK;
        async16(gA0 + ko, &As3[buf][wv * 1024]);
        async16(gA1 + ko, &As3[buf][wv * 1024 + 512]);
        async16(gB0 + ko, &Bs3[buf][wv * 1024]);
        async16(gB1 + ko, &Bs3[buf][wv * 1024 + 512]);
    };

    // tiles 0 and 1 in flight before the prologue barrier (which drains them)
    issue(0);
    issue(1);

    // ---- prologue ----
    if (t < BM) {
        const int i = rowBase + t;
        int l = 0, r = NG + 1;
        while (l < r) { int m = (l + r) >> 1; if (sse[m] <= i) l = m + 1; else r = m; }
        segRow[t] = l - 1;
    }
    if (t >= BM && t < BM + 3) bnd[t - BM] = BM;
    for (int idx = t; idx < 4 * (BN + 4); idx += 256) ((int*)Pmax)[idx] = 0;
    __syncthreads();                // full drain: tiles 0,1 resident after this
    if (t < BM - 1) {
        const int s0 = segRow[t], s1 = segRow[t + 1];
        if (s1 != s0) bnd[s1 - segRow[0] - 1] = t + 1;   // visible after next barrier
    }

    floatx4 acc[4][4];
#pragma unroll
    for (int m = 0; m < 4; ++m)
#pragma unroll
        for (int n = 0; n < 4; ++n) acc[m][n] = (floatx4){0.f, 0.f, 0.f, 0.f};

    // ---- K loop: issue(k+2) -> compute(k) -> waitcnt(vmcnt 4, lgkm 0)+barrier ----
    // vmcnt(4): retires tile k+1's DMA (oldest 4), leaves tile k+2 in flight
    // across the barrier. lgkmcnt(0): REQUIRED — drains this wave's ds_reads of
    // buffer (k)%3 so the next iteration's DMA into buffer (k)%3... (3-phase
    // rotation: the DMA issued in iter k+1 targets buffer k%3) cannot land
    // under a still-pending ds_read (the r6 race).
    for (int kt = 0; kt < KT; ++kt) {
        if (kt + 2 < KT) issue(kt + 2);

        const unsigned short* A = As3[kt % 3];
        const unsigned short* B = Bs3[kt % 3];
        bf16x8 af[4], bfr[4];
#pragma unroll
        for (int mt = 0; mt < 4; ++mt) {
            const int R = wr + mt * 16 + lcol;
            const int pc = lquad ^ ((R >> 1) & 3);
            af[mt] = *(const bf16x8*)&A[R * 32 + pc * 8];
        }
#pragma unroll
        for (int nt = 0; nt < 4; ++nt) {
            const int R = wc + nt * 16 + lcol;
            const int pc = lquad ^ ((R >> 1) & 3);
            bfr[nt] = *(const bf16x8*)&B[R * 32 + pc * 8];
        }
#pragma unroll
        for (int mt = 0; mt < 4; ++mt)
#pragma unroll
            for (int nt = 0; nt < 4; ++nt)
                acc[mt][nt] = __builtin_amdgcn_mfma_f32_16x16x32_bf16(af[mt], bfr[nt], acc[mt][nt], 0, 0, 0);

        if (kt + 2 < KT) {
            asm volatile("s_waitcnt vmcnt(4) lgkmcnt(0)\n\ts_barrier" ::: "memory");
        } else {
            asm volatile("s_waitcnt vmcnt(0) lgkmcnt(0)\n\ts_barrier" ::: "memory");
        }
    }

    // ---- epilogue: bias + relu + segment-max (proven) ----
    const int b0 = bnd[0], b1 = bnd[1], b2 = bnd[2];
    const int segBase = segRow[0];

#pragma unroll
    for (int nt = 0; nt < 4; ++nt) {
        const int col  = wc + nt * 16 + lcol;
        const float bias = bm[cTile + col];
        float pm[4] = {0.f, 0.f, 0.f, 0.f};
#pragma unroll
        for (int mt = 0; mt < 4; ++mt) {
#pragma unroll
            for (int r = 0; r < 4; ++r) {
                const int lr = wr + mt * 16 + lquad * 4 + r;
                const int ls = (lr >= b0) + (lr >= b1) + (lr >= b2);
                const float v = fmaxf(acc[mt][nt][r] + bias, 0.f);
                pm[ls] = fmaxf(pm[ls], v);
            }
        }
#pragma unroll
        for (int ls = 0; ls < 4; ++ls)
            if (pm[ls] > 0.f)
                atomicMax(&Pmax[ls][col], __float_as_int(pm[ls]));
    }
    __syncthreads();

    for (int idx = t; idx < 4 * BN; idx += 256) {
        const int ls = idx >> 7, col = idx & 127;
        if (ls > 0 && bnd[ls - 1] >= BM) continue;
        const int seg = segBase + ls;
        const int v   = Pmax[ls][col];
        const int gs  = sse[seg], ge = sse[seg + 1];
        float* dst = &out[(size_t)seg * H + cTile + col];
        if (gs >= rowBase && ge <= rowBase + BM) {
            *dst = __int_as_float(v);
        } else {
            atomicMax((int*)dst, v);
        }
    }
}

// ---------------- fallback (round-2 kernel; only if ws too small) ----------------
constexpr int LDAF = 40;
__global__ __launch_bounds__(256) void pool_mfma_fb(
    const float* __restrict__ hist_enc, const float* __restrict__ pos,
    const int* __restrict__ sse, const float* __restrict__ Ws,
    const float* __restrict__ bs, const unsigned short* __restrict__ WmT,
    const float* __restrict__ bm, float* __restrict__ out)
{
    __shared__ __attribute__((aligned(16))) unsigned short As[BM][LDAF];
    __shared__ __attribute__((aligned(16))) unsigned short Bs[BN][LDAF];
    __shared__ float relRow[BM][2];
    __shared__ int   segRow[BM];
    __shared__ int   bnd[3];
    __shared__ int   Pmax[4][BN + 4];

    const int t = threadIdx.x;
    const int cTile = blockIdx.x * BN;
    const int rowBase = blockIdx.y * BM;

    if (t < BM) {
        const int i = rowBase + t;
        int l = 0, r = NG + 1;
        while (l < r) { int m = (l + r) >> 1; if (sse[m] <= i) l = m + 1; else r = m; }
        const int g = l - 1;
        segRow[t] = g;
        const int a = sse[g];
        relRow[t][0] = pos[2 * i + 0] - pos[2 * a + 0];
        relRow[t][1] = pos[2 * i + 1] - pos[2 * a + 1];
    }
    if (t >= BM && t < BM + 3) bnd[t - BM] = BM;
    for (int idx = t; idx < 4 * (BN + 4); idx += 256) ((int*)Pmax)[idx] = 0;
    __syncthreads();
    if (t < BM - 1) {
        const int s0 = segRow[t], s1 = segRow[t + 1];
        if (s1 != s0) bnd[s1 - segRow[0] - 1] = t + 1;
    }

    const int lane = t & 63, wv = t >> 6;
    const int wr = (wv >> 1) * 64, wc = (wv & 1) * 64;
    const int lcol = lane & 15, lquad = lane >> 4;

    floatx4 acc[4][4];
#pragma unroll
    for (int m = 0; m < 4; ++m)
#pragma unroll
        for (int n = 0; n < 4; ++n) acc[m][n] = (floatx4){0.f, 0.f, 0.f, 0.f};

    for (int kt = 0; kt < KD / BK; ++kt) {
        const int k0 = kt * BK;
        float4 av[4]; uint4 bv[2];
        if (k0 < H) {
#pragma unroll
            for (int i = 0; i < 4; ++i) {
                const int idx = i * 256 + t;
                const int row = idx >> 3, kq = (idx & 7) * 4;
                av[i] = *(const float4*)&hist_enc[(size_t)(rowBase + row) * H + k0 + kq];
            }
        } else {
#pragma unroll
            for (int i = 0; i < 4; ++i) {
                const int idx = i * 256 + t;
                const int row = idx >> 3, kq = (idx & 7) * 4;
                const int e = k0 - H + kq;
                const float4 w0 = *(const float4*)&Ws[e];
                const float4 w1 = *(const float4*)&Ws[E + e];
                const float4 b4 = *(const float4*)&bs[e];
                const float r0 = relRow[row][0], r1 = relRow[row][1];
                av[i].x = fmaxf(r0 * w0.x + r1 * w1.x + b4.x, 0.f);
                av[i].y = fmaxf(r0 * w0.y + r1 * w1.y + b4.y, 0.f);
                av[i].z = fmaxf(r0 * w0.z + r1 * w1.z + b4.z, 0.f);
                av[i].w = fmaxf(r0 * w0.w + r1 * w1.w + b4.w, 0.f);
            }
        }
#pragma unroll
        for (int i = 0; i < 2; ++i) {
            const int idx = i * 256 + t;
            const int n = idx >> 2, q = idx & 3;
            bv[i] = *(const uint4*)&WmT[(size_t)(cTile + n) * KD + k0 + q * 8];
        }
        __syncthreads();
#pragma unroll
        for (int i = 0; i < 4; ++i) {
            const int idx = i * 256 + t;
            const int row = idx >> 3, kq = (idx & 7) * 4;
            ushort4 p;
            p.x = f2bf(av[i].x); p.y = f2bf(av[i].y);
            p.z = f2bf(av[i].z); p.w = f2bf(av[i].w);
            *(ushort4*)&As[row][kq] = p;
        }
#pragma unroll
        for (int i = 0; i < 2; ++i) {
            const int idx = i * 256 + t;
            const int n = idx >> 2, q = idx & 3;
            *(uint4*)&Bs[n][q * 8] = bv[i];
        }
        __syncthreads();

        bf16x8 af[4], bfr[4];
#pragma unroll
        for (int mt = 0; mt < 4; ++mt)
            af[mt] = *(const bf16x8*)&As[wr + mt * 16 + lcol][lquad * 8];
#pragma unroll
        for (int nt = 0; nt < 4; ++nt)
            bfr[nt] = *(const bf16x8*)&Bs[wc + nt * 16 + lcol][lquad * 8];
#pragma unroll
        for (int mt = 0; mt < 4; ++mt)
#pragma unroll
            for (int nt = 0; nt < 4; ++nt)
                acc[mt][nt] = __builtin_amdgcn_mfma_f32_16x16x32_bf16(af[mt], bfr[nt], acc[mt][nt], 0, 0, 0);
    }

    const int b0 = bnd[0], b1 = bnd[1], b2 = bnd[2];
    const int segBase = segRow[0];
#pragma unroll
    for (int nt = 0; nt < 4; ++nt) {
        const int col = wc + nt * 16 + lcol;
        const float bias = bm[cTile + col];
        float pm[4] = {0.f, 0.f, 0.f, 0.f};
#pragma unroll
        for (int mt = 0; mt < 4; ++mt) {
#pragma unroll
            for (int r = 0; r < 4; ++r) {
                const int lr = wr + mt * 16 + lquad * 4 + r;
                const int ls = (lr >= b0) + (lr >= b1) + (lr >= b2);
                const float v = fmaxf(acc[mt][nt][r] + bias, 0.f);
                pm[ls] = fmaxf(pm[ls], v);
            }
        }
#pragma unroll
        for (int ls = 0; ls < 4; ++ls)
            if (pm[ls] > 0.f) atomicMax(&Pmax[ls][col], __float_as_int(pm[ls]));
    }
    __syncthreads();
    for (int idx = t; idx < 4 * BN; idx += 256) {
        const int ls = idx >> 7, col = idx & 127;
        if (ls > 0 && bnd[ls - 1] >= BM) continue;
        const int seg = segBase + ls;
        const int v = Pmax[ls][col];
        const int gs = sse[seg], ge = sse[seg + 1];
        float* dst = &out[(size_t)seg * H + cTile + col];
        if (gs >= rowBase && ge <= rowBase + BM) *dst = __int_as_float(v);
        else atomicMax((int*)dst, v);
    }
}

extern "C" void kernel_launch(void* const* d_in, const int* in_sizes, int n_in,
                              void* d_out, int out_size, void* d_ws, size_t ws_size,
                              hipStream_t stream) {
    const float* hist_enc = (const float*)d_in[0];
    const float* pos      = (const float*)d_in[1];
    const int*   sse      = (const int*)  d_in[2];
    const float* Ws       = (const float*)d_in[3];
    const float* bs       = (const float*)d_in[4];
    const float* Wm       = (const float*)d_in[5];
    const float* bm       = (const float*)d_in[6];
    float*       out      = (float*)d_out;

    const size_t needWmT = (size_t)H * KD * 2;     // 655,360 B
    const size_t needA   = (size_t)NR * KD * 2;    // 131,072,000 B
    unsigned short* WmT  = (unsigned short*)d_ws;
    unsigned short* Abf  = (unsigned short*)((char*)d_ws + needWmT);

    hipMemsetAsync(out, 0, (size_t)out_size * sizeof(float), stream);

    if (ws_size >= needWmT + needA) {
        prep<<<880, 256, 0, stream>>>(hist_enc, pos, sse, Ws, bs, Wm, WmT, Abf, 1);
        pool_mfma5<<<3200, 256, 0, stream>>>(Abf, sse, WmT, bm, out);
    } else {
        prep<<<80, 256, 0, stream>>>(hist_enc, pos, sse, Ws, bs, Wm, WmT, Abf, 0);
        pool_mfma_fb<<<dim3(H / BN, NR / BM), 256, 0, stream>>>(hist_enc, pos, sse, Ws, bs, WmT, bm, out);
    }
}

// Round 8
// 440.212 us; speedup vs baseline: 1.1469x; 1.1469x over previous
//
#include <hip/hip_runtime.h>

// PoolHiddenNet round 8: r5's proven GEMM body (dbuf distance-1 __syncthreads
// pipeline, XCD swizzle, XOR bank swizzle, segment-max epilogue) with the
// per-block binary search hoisted into prep (segArr, coalesced load in GEMM).
// Prep rebuilt: 3200 blocks x 32 rows (12.5 blocks/CU) + v_perm_b32 packing
// (3 VALU per 2 elems, round-half-up — same class r4 validated).
// r6/r7 lesson: distance-2 vmcnt pipelines regress on this K-loop; keep r5 shape.

typedef __bf16 bf16x8 __attribute__((ext_vector_type(8)));
typedef float floatx4 __attribute__((ext_vector_type(4)));

constexpr int NR = 102400;
constexpr int NG = 2048;
constexpr int E  = 128;
constexpr int H  = 512;
constexpr int KD = 640;
constexpr int BM = 128, BN = 128, BK = 32;

__device__ inline unsigned short f2bf(float f) {
    unsigned u = __float_as_uint(f);
    u += 0x7FFF + ((u >> 16) & 1u);   // RNE (finite inputs)
    return (unsigned short)(u >> 16);
}

// pack two fp32 -> bf16x2, round-half-up: 2x v_add + 1x v_perm_b32
__device__ inline unsigned pk2(float lo, float hi) {
    return __builtin_amdgcn_perm(__float_as_uint(hi) + 0x8000u,
                                 __float_as_uint(lo) + 0x8000u, 0x07060302u);
}

__device__ inline void async16(const void* g, void* l) {
    __builtin_amdgcn_global_load_lds(
        (const __attribute__((address_space(1))) unsigned int*)g,
        (__attribute__((address_space(3))) unsigned int*)l, 16, 0, 0);
}

// ---------------- prep: Abf+segArr (3200 blocks x 32 rows) + WmT transpose (80) ----------------
__global__ __launch_bounds__(256) void prep2(
    const float* __restrict__ hist_enc, const float* __restrict__ pos,
    const int* __restrict__ sse, const float* __restrict__ Ws,
    const float* __restrict__ bs, const float* __restrict__ Wm,
    unsigned short* __restrict__ WmT, unsigned short* __restrict__ Abf,
    int* __restrict__ segArr, int doAbf)
{
    const int b = blockIdx.x;
    const int t = threadIdx.x;
    if (doAbf && b < 3200) {
        __shared__ float relRow[32][2];
        const int rowBase = b * 32;
        if (t < 32) {
            const int i = rowBase + t;
            int l = 0, r = NG + 1;
            while (l < r) { int m = (l + r) >> 1; if (sse[m] <= i) l = m + 1; else r = m; }
            const int g = l - 1;
            if (segArr) segArr[i] = g;
            const int a = sse[g];
            relRow[t][0] = pos[2 * i + 0] - pos[2 * a + 0];
            relRow[t][1] = pos[2 * i + 1] - pos[2 * a + 1];
        }
        __syncthreads();
        // hist: 32 rows x 512 = 2048 8-elem chunks
#pragma unroll
        for (int j = 0; j < 8; ++j) {
            const int c = j * 256 + t;
            const int row = c >> 6, col = (c & 63) * 8;
            const float4 f0 = *(const float4*)&hist_enc[(size_t)(rowBase + row) * H + col];
            const float4 f1 = *(const float4*)&hist_enc[(size_t)(rowBase + row) * H + col + 4];
            uint4 u;
            u.x = pk2(f0.x, f0.y); u.y = pk2(f0.z, f0.w);
            u.z = pk2(f1.x, f1.y); u.w = pk2(f1.z, f1.w);
            *(uint4*)&Abf[(size_t)(rowBase + row) * KD + col] = u;
        }
        // emb: 32 rows x 128 = 512 8-elem chunks
#pragma unroll
        for (int j = 0; j < 2; ++j) {
            const int c = j * 256 + t;
            const int row = c >> 4, e = (c & 15) * 8;
            const float r0 = relRow[row][0], r1 = relRow[row][1];
            const float4 w0a = *(const float4*)&Ws[e],     w0b = *(const float4*)&Ws[e + 4];
            const float4 w1a = *(const float4*)&Ws[E + e], w1b = *(const float4*)&Ws[E + e + 4];
            const float4 ba  = *(const float4*)&bs[e],     bb  = *(const float4*)&bs[e + 4];
            const float v0 = fmaxf(r0 * w0a.x + r1 * w1a.x + ba.x, 0.f);
            const float v1 = fmaxf(r0 * w0a.y + r1 * w1a.y + ba.y, 0.f);
            const float v2 = fmaxf(r0 * w0a.z + r1 * w1a.z + ba.z, 0.f);
            const float v3 = fmaxf(r0 * w0a.w + r1 * w1a.w + ba.w, 0.f);
            const float v4 = fmaxf(r0 * w0b.x + r1 * w1b.x + bb.x, 0.f);
            const float v5 = fmaxf(r0 * w0b.y + r1 * w1b.y + bb.y, 0.f);
            const float v6 = fmaxf(r0 * w0b.z + r1 * w1b.z + bb.z, 0.f);
            const float v7 = fmaxf(r0 * w0b.w + r1 * w1b.w + bb.w, 0.f);
            uint4 u;
            u.x = pk2(v0, v1); u.y = pk2(v2, v3);
            u.z = pk2(v4, v5); u.w = pk2(v6, v7);
            *(uint4*)&Abf[(size_t)(rowBase + row) * KD + H + e] = u;
        }
    } else {
        const int bb = doAbf ? (b - 3200) : b;
        if (bb < 0 || bb >= 80) return;
        __shared__ float tile[64][65];
        const int kb = (bb % 10) * 64, nb = (bb / 10) * 64;
        const int tx = t & 63, tq = t >> 6;
#pragma unroll
        for (int i = 0; i < 16; ++i) {
            const int k = tq * 16 + i;
            tile[k][tx] = Wm[(size_t)(kb + k) * H + nb + tx];
        }
        __syncthreads();
#pragma unroll
        for (int i = 0; i < 16; ++i) {
            const int n = tq * 16 + i;
            WmT[(size_t)(nb + n) * KD + kb + tx] = f2bf(tile[tx][n]);
        }
    }
}

// ---------------- main: GEMM + segment-max (r5 body + segArr prologue) ----------------
__global__ __launch_bounds__(256) void pool_mfma6(
    const unsigned short* __restrict__ Abf,   // (NR, 640) bf16
    const int*   __restrict__ sse,
    const int*   __restrict__ segArr,         // (NR,) seg id per row, or nullptr
    const unsigned short* __restrict__ WmT,   // (512, 640) bf16
    const float* __restrict__ bm,
    float*       __restrict__ out)            // (2048, 512) fp32, zeroed
{
    __shared__ __attribute__((aligned(16))) unsigned short As2[2][BM * BK]; // 2 x 8 KB
    __shared__ __attribute__((aligned(16))) unsigned short Bs2[2][BN * BK]; // 2 x 8 KB
    __shared__ int segRow[BM];
    __shared__ int bnd[3];
    __shared__ int Pmax[4][BN + 4];

    const int t = threadIdx.x;
    // XCD swizzle (proven r4/r5): 4 column-siblings of a row-tile share bid%8.
    const int bid     = blockIdx.x;
    const int rowTile = (bid >> 5) * 8 + (bid & 7);
    const int colTile = (bid >> 3) & 3;
    const int rowBase = rowTile * BM;
    const int cTile   = colTile * BN;

    const int lane  = t & 63;
    const int wv    = t >> 6;
    const int wr    = (wv >> 1) * 64;
    const int wc    = (wv & 1) * 64;
    const int lcol  = lane & 15;
    const int lquad = lane >> 4;

    // DMA staging (r3/r5-proven): wave wv stages rows [wv*32, wv*32+32);
    // source chunk XOR-swizzled so fragment ds_read_b128 is ~2-way only.
    const int sRow0 = wv * 32 + (lane >> 2);
    const int sRow1 = sRow0 + 16;
    const int phys  = lane & 3;
    const int cl0   = phys ^ ((sRow0 >> 1) & 3);
    const int cl1   = phys ^ ((sRow1 >> 1) & 3);
    const unsigned short* gA0 = Abf + (size_t)(rowBase + sRow0) * KD + cl0 * 8;
    const unsigned short* gA1 = Abf + (size_t)(rowBase + sRow1) * KD + cl1 * 8;
    const unsigned short* gB0 = WmT + (size_t)(cTile + sRow0) * KD + cl0 * 8;
    const unsigned short* gB1 = WmT + (size_t)(cTile + sRow1) * KD + cl1 * 8;

    auto issue = [&](int kt, int buf) {
        const int ko = kt * BK;
        async16(gA0 + ko, &As2[buf][wv * 1024]);
        async16(gA1 + ko, &As2[buf][wv * 1024 + 512]);
        async16(gB0 + ko, &Bs2[buf][wv * 1024]);
        async16(gB1 + ko, &Bs2[buf][wv * 1024 + 512]);
    };

    // kick off tile 0; prologue absorbs its latency
    issue(0, 0);

    // ---- prologue: coalesced segArr load (search hoisted into prep) ----
    if (segArr) {
        if (t < BM) segRow[t] = segArr[rowBase + t];
    } else if (t < BM) {
        const int i = rowBase + t;
        int l = 0, r = NG + 1;
        while (l < r) { int m = (l + r) >> 1; if (sse[m] <= i) l = m + 1; else r = m; }
        segRow[t] = l - 1;
    }
    if (t >= BM && t < BM + 3) bnd[t - BM] = BM;
    for (int idx = t; idx < 4 * (BN + 4); idx += 256) ((int*)Pmax)[idx] = 0;
    __syncthreads();
    if (t < BM - 1) {
        const int s0 = segRow[t], s1 = segRow[t + 1];
        if (s1 != s0) bnd[s1 - segRow[0] - 1] = t + 1;   // visible after next barrier
    }

    floatx4 acc[4][4];
#pragma unroll
    for (int m = 0; m < 4; ++m)
#pragma unroll
        for (int n = 0; n < 4; ++n) acc[m][n] = (floatx4){0.f, 0.f, 0.f, 0.f};

    // ---- K loop: distance-1 double-buffered DMA (r5-proven) ----
    for (int kt = 0; kt < KD / BK; ++kt) {
        __syncthreads();                       // drains tile kt's DMA; frees buf (kt+1)&1
        if (kt < KD / BK - 1) issue(kt + 1, (kt + 1) & 1);

        const unsigned short* A = As2[kt & 1];
        const unsigned short* B = Bs2[kt & 1];
        bf16x8 af[4], bfr[4];
#pragma unroll
        for (int mt = 0; mt < 4; ++mt) {
            const int R = wr + mt * 16 + lcol;
            const int pc = lquad ^ ((R >> 1) & 3);
            af[mt] = *(const bf16x8*)&A[R * 32 + pc * 8];
        }
#pragma unroll
        for (int nt = 0; nt < 4; ++nt) {
            const int R = wc + nt * 16 + lcol;
            const int pc = lquad ^ ((R >> 1) & 3);
            bfr[nt] = *(const bf16x8*)&B[R * 32 + pc * 8];
        }
#pragma unroll
        for (int mt = 0; mt < 4; ++mt)
#pragma unroll
            for (int nt = 0; nt < 4; ++nt)
                acc[mt][nt] = __builtin_amdgcn_mfma_f32_16x16x32_bf16(af[mt], bfr[nt], acc[mt][nt], 0, 0, 0);
    }

    // ---- epilogue: bias + relu + segment-max (proven) ----
    const int b0 = bnd[0], b1 = bnd[1], b2 = bnd[2];
    const int segBase = segRow[0];

#pragma unroll
    for (int nt = 0; nt < 4; ++nt) {
        const int col  = wc + nt * 16 + lcol;
        const float bias = bm[cTile + col];
        float pm[4] = {0.f, 0.f, 0.f, 0.f};
#pragma unroll
        for (int mt = 0; mt < 4; ++mt) {
#pragma unroll
            for (int r = 0; r < 4; ++r) {
                const int lr = wr + mt * 16 + lquad * 4 + r;
                const int ls = (lr >= b0) + (lr >= b1) + (lr >= b2);
                const float v = fmaxf(acc[mt][nt][r] + bias, 0.f);
                pm[ls] = fmaxf(pm[ls], v);
            }
        }
#pragma unroll
        for (int ls = 0; ls < 4; ++ls)
            if (pm[ls] > 0.f)
                atomicMax(&Pmax[ls][col], __float_as_int(pm[ls]));
    }
    __syncthreads();

    for (int idx = t; idx < 4 * BN; idx += 256) {
        const int ls = idx >> 7, col = idx & 127;
        if (ls > 0 && bnd[ls - 1] >= BM) continue;
        const int seg = segBase + ls;
        const int v   = Pmax[ls][col];
        const int gs  = sse[seg], ge = sse[seg + 1];
        float* dst = &out[(size_t)seg * H + cTile + col];
        if (gs >= rowBase && ge <= rowBase + BM) {
            *dst = __int_as_float(v);
        } else {
            atomicMax((int*)dst, v);
        }
    }
}

// ---------------- fallback (round-2 kernel; only if ws too small) ----------------
constexpr int LDAF = 40;
__global__ __launch_bounds__(256) void pool_mfma_fb(
    const float* __restrict__ hist_enc, const float* __restrict__ pos,
    const int* __restrict__ sse, const float* __restrict__ Ws,
    const float* __restrict__ bs, const unsigned short* __restrict__ WmT,
    const float* __restrict__ bm, float* __restrict__ out)
{
    __shared__ __attribute__((aligned(16))) unsigned short As[BM][LDAF];
    __shared__ __attribute__((aligned(16))) unsigned short Bs[BN][LDAF];
    __shared__ float relRow[BM][2];
    __shared__ int   segRow[BM];
    __shared__ int   bnd[3];
    __shared__ int   Pmax[4][BN + 4];

    const int t = threadIdx.x;
    const int cTile = blockIdx.x * BN;
    const int rowBase = blockIdx.y * BM;

    if (t < BM) {
        const int i = rowBase + t;
        int l = 0, r = NG + 1;
        while (l < r) { int m = (l + r) >> 1; if (sse[m] <= i) l = m + 1; else r = m; }
        const int g = l - 1;
        segRow[t] = g;
        const int a = sse[g];
        relRow[t][0] = pos[2 * i + 0] - pos[2 * a + 0];
        relRow[t][1] = pos[2 * i + 1] - pos[2 * a + 1];
    }
    if (t >= BM && t < BM + 3) bnd[t - BM] = BM;
    for (int idx = t; idx < 4 * (BN + 4); idx += 256) ((int*)Pmax)[idx] = 0;
    __syncthreads();
    if (t < BM - 1) {
        const int s0 = segRow[t], s1 = segRow[t + 1];
        if (s1 != s0) bnd[s1 - segRow[0] - 1] = t + 1;
    }

    const int lane = t & 63, wv = t >> 6;
    const int wr = (wv >> 1) * 64, wc = (wv & 1) * 64;
    const int lcol = lane & 15, lquad = lane >> 4;

    floatx4 acc[4][4];
#pragma unroll
    for (int m = 0; m < 4; ++m)
#pragma unroll
        for (int n = 0; n < 4; ++n) acc[m][n] = (floatx4){0.f, 0.f, 0.f, 0.f};

    for (int kt = 0; kt < KD / BK; ++kt) {
        const int k0 = kt * BK;
        float4 av[4]; uint4 bv[2];
        if (k0 < H) {
#pragma unroll
            for (int i = 0; i < 4; ++i) {
                const int idx = i * 256 + t;
                const int row = idx >> 3, kq = (idx & 7) * 4;
                av[i] = *(const float4*)&hist_enc[(size_t)(rowBase + row) * H + k0 + kq];
            }
        } else {
#pragma unroll
            for (int i = 0; i < 4; ++i) {
                const int idx = i * 256 + t;
                const int row = idx >> 3, kq = (idx & 7) * 4;
                const int e = k0 - H + kq;
                const float4 w0 = *(const float4*)&Ws[e];
                const float4 w1 = *(const float4*)&Ws[E + e];
                const float4 b4 = *(const float4*)&bs[e];
                const float r0 = relRow[row][0], r1 = relRow[row][1];
                av[i].x = fmaxf(r0 * w0.x + r1 * w1.x + b4.x, 0.f);
                av[i].y = fmaxf(r0 * w0.y + r1 * w1.y + b4.y, 0.f);
                av[i].z = fmaxf(r0 * w0.z + r1 * w1.z + b4.z, 0.f);
                av[i].w = fmaxf(r0 * w0.w + r1 * w1.w + b4.w, 0.f);
            }
        }
#pragma unroll
        for (int i = 0; i < 2; ++i) {
            const int idx = i * 256 + t;
            const int n = idx >> 2, q = idx & 3;
            bv[i] = *(const uint4*)&WmT[(size_t)(cTile + n) * KD + k0 + q * 8];
        }
        __syncthreads();
#pragma unroll
        for (int i = 0; i < 4; ++i) {
            const int idx = i * 256 + t;
            const int row = idx >> 3, kq = (idx & 7) * 4;
            ushort4 p;
            p.x = f2bf(av[i].x); p.y = f2bf(av[i].y);
            p.z = f2bf(av[i].z); p.w = f2bf(av[i].w);
            *(ushort4*)&As[row][kq] = p;
        }
#pragma unroll
        for (int i = 0; i < 2; ++i) {
            const int idx = i * 256 + t;
            const int n = idx >> 2, q = idx & 3;
            *(uint4*)&Bs[n][q * 8] = bv[i];
        }
        __syncthreads();

        bf16x8 af[4], bfr[4];
#pragma unroll
        for (int mt = 0; mt < 4; ++mt)
            af[mt] = *(const bf16x8*)&As[wr + mt * 16 + lcol][lquad * 8];
#pragma unroll
        for (int nt = 0; nt < 4; ++nt)
            bfr[nt] = *(const bf16x8*)&Bs[wc + nt * 16 + lcol][lquad * 8];
#pragma unroll
        for (int mt = 0; mt < 4; ++mt)
#pragma unroll
            for (int nt = 0; nt < 4; ++nt)
                acc[mt][nt] = __builtin_amdgcn_mfma_f32_16x16x32_bf16(af[mt], bfr[nt], acc[mt][nt], 0, 0, 0);
    }

    const int b0 = bnd[0], b1 = bnd[1], b2 = bnd[2];
    const int segBase = segRow[0];
#pragma unroll
    for (int nt = 0; nt < 4; ++nt) {
        const int col = wc + nt * 16 + lcol;
        const float bias = bm[cTile + col];
        float pm[4] = {0.f, 0.f, 0.f, 0.f};
#pragma unroll
        for (int mt = 0; mt < 4; ++mt) {
#pragma unroll
            for (int r = 0; r < 4; ++r) {
                const int lr = wr + mt * 16 + lquad * 4 + r;
                const int ls = (lr >= b0) + (lr >= b1) + (lr >= b2);
                const float v = fmaxf(acc[mt][nt][r] + bias, 0.f);
                pm[ls] = fmaxf(pm[ls], v);
            }
        }
#pragma unroll
        for (int ls = 0; ls < 4; ++ls)
            if (pm[ls] > 0.f) atomicMax(&Pmax[ls][col], __float_as_int(pm[ls]));
    }
    __syncthreads();
    for (int idx = t; idx < 4 * BN; idx += 256) {
        const int ls = idx >> 7, col = idx & 127;
        if (ls > 0 && bnd[ls - 1] >= BM) continue;
        const int seg = segBase + ls;
        const int v = Pmax[ls][col];
        const int gs = sse[seg], ge = sse[seg + 1];
        float* dst = &out[(size_t)seg * H + cTile + col];
        if (gs >= rowBase && ge <= rowBase + BM) *dst = __int_as_float(v);
        else atomicMax((int*)dst, v);
    }
}

extern "C" void kernel_launch(void* const* d_in, const int* in_sizes, int n_in,
                              void* d_out, int out_size, void* d_ws, size_t ws_size,
                              hipStream_t stream) {
    const float* hist_enc = (const float*)d_in[0];
    const float* pos      = (const float*)d_in[1];
    const int*   sse      = (const int*)  d_in[2];
    const float* Ws       = (const float*)d_in[3];
    const float* bs       = (const float*)d_in[4];
    const float* Wm       = (const float*)d_in[5];
    const float* bm       = (const float*)d_in[6];
    float*       out      = (float*)d_out;

    const size_t needWmT = (size_t)H * KD * 2;     // 655,360 B
    const size_t needA   = (size_t)NR * KD * 2;    // 131,072,000 B
    const size_t needSeg = (size_t)NR * 4;         // 409,600 B
    unsigned short* WmT  = (unsigned short*)d_ws;
    unsigned short* Abf  = (unsigned short*)((char*)d_ws + needWmT);
    int*            segA = (int*)((char*)d_ws + needWmT + needA);

    hipMemsetAsync(out, 0, (size_t)out_size * sizeof(float), stream);

    if (ws_size >= needWmT + needA + needSeg) {
        prep2<<<3280, 256, 0, stream>>>(hist_enc, pos, sse, Ws, bs, Wm, WmT, Abf, segA, 1);
        pool_mfma6<<<3200, 256, 0, stream>>>(Abf, sse, segA, WmT, bm, out);
    } else if (ws_size >= needWmT + needA) {
        prep2<<<3280, 256, 0, stream>>>(hist_enc, pos, sse, Ws, bs, Wm, WmT, Abf, nullptr, 1);
        pool_mfma6<<<3200, 256, 0, stream>>>(Abf, sse, nullptr, WmT, bm, out);
    } else {
        prep2<<<80, 256, 0, stream>>>(hist_enc, pos, sse, Ws, bs, Wm, WmT, Abf, nullptr, 0);
        pool_mfma_fb<<<dim3(H / BN, NR / BM), 256, 0, stream>>>(hist_enc, pos, sse, Ws, bs, WmT, bm, out);
    }
}